// Round 5
// baseline (1059.148 us; speedup 1.0000x reference)
//
#include <hip/hip_runtime.h>
#include <stdint.h>

typedef unsigned short u16;
typedef float f32x4 __attribute__((ext_vector_type(4)));
typedef __bf16 bf16x8 __attribute__((ext_vector_type(8)));

#define B_ 4096
#define D_ 2048
#define U_ 2048
#define K_ 4096   // D + U
#define N_ 8192   // 4*U
#define NT 128    // K/32 K-tiles

__device__ __forceinline__ u16 f32_bf16(float f) {
  uint32_t u = __float_as_uint(f);
  u += 0x7FFFu + ((u >> 16) & 1u);
  return (u16)(u >> 16);
}
__device__ __forceinline__ float hsig(float x) {
  return fminf(fmaxf(0.2f * x + 0.5f, 0.0f), 1.0f);
}
__device__ __forceinline__ float ftanh(float x) {
  x = fminf(fmaxf(x, -15.0f), 15.0f);
  float e = __expf(2.0f * x);
  return (e - 1.0f) / (e + 1.0f);
}
__device__ __forceinline__ void gload16(const void* g, void* l) {
  __builtin_amdgcn_global_load_lds(
      (const __attribute__((address_space(1))) void*)g,
      (__attribute__((address_space(3))) void*)l,
      16, 0, 0);
}

// ---- cast A = [inputs | h_tm1] -> bf16 [4096][4096] ----
__global__ __launch_bounds__(256) void cast_a(const float* __restrict__ x,
                                              const float* __restrict__ h,
                                              u16* __restrict__ A) {
  int c = blockIdx.x * 256 + threadIdx.x;
  int m = c >> 9;
  int kc = (c & 511) << 3;
  const float* src = (kc < D_) ? (x + (size_t)m * D_ + kc)
                               : (h + (size_t)m * U_ + (kc - D_));
  float4 v0 = ((const float4*)src)[0];
  float4 v1 = ((const float4*)src)[1];
  u16 o[8] = { f32_bf16(v0.x), f32_bf16(v0.y), f32_bf16(v0.z), f32_bf16(v0.w),
               f32_bf16(v1.x), f32_bf16(v1.y), f32_bf16(v1.z), f32_bf16(v1.w) };
  *(uint4*)(A + (size_t)c * 8) = *(const uint4*)o;
}

// ---- cast + transpose + gate-interleave W -> Wt[n'][k] bf16 [8192][4096] ----
// n' = ublk*64 + g*16 + ul  where u = ublk*16 + ul, original col n = g*2048 + u
__global__ __launch_bounds__(256) void cast_wt(const float* __restrict__ kern,
                                               const float* __restrict__ rker,
                                               u16* __restrict__ Wt) {
  __shared__ u16 sW[64][68];
  const int t = threadIdx.x;
  const int bx = blockIdx.x;   // ublk 0..127
  const int by = blockIdx.y;   // k block 0..63
  const int k0 = by * 64;
  const float* src = (k0 < D_) ? kern : rker;
  const int krow0 = (k0 < D_) ? k0 : (k0 - D_);
#pragma unroll
  for (int i = 0; i < 4; ++i) {
    int c = i * 256 + t;
    int kl = c >> 4;
    int nq = c & 15;
    int g  = nq >> 2;
    int ul = (nq & 3) << 2;
    int n  = g * U_ + bx * 16 + ul;
    float4 v = *(const float4*)(src + (size_t)(krow0 + kl) * N_ + n);
    u16 p[4] = { f32_bf16(v.x), f32_bf16(v.y), f32_bf16(v.z), f32_bf16(v.w) };
    *(ushort4*)&sW[kl][g * 16 + ul] = *(const ushort4*)p;
  }
  __syncthreads();
#pragma unroll
  for (int j = 0; j < 2; ++j) {
    int c2 = j * 256 + t;
    int nl = c2 >> 3;
    int kc = c2 & 7;
    u16 p[8];
#pragma unroll
    for (int jj = 0; jj < 8; ++jj) p[jj] = sW[kc * 8 + jj][nl];
    *(uint4*)(Wt + ((size_t)bx * 64 + nl) * K_ + k0 + kc * 8) = *(const uint4*)p;
  }
}

// ===== 256x128 triple-buffered BK=32 GEMM (16x16x32 MFMA) + LSTM epilogue =====
// LDS: 3 buffers x (A[256][32] 16K + B[128][32] 8K) = 72 KiB -> 2 blocks/CU.
// Row = 64B = 4 x 16B chunks; phys_chunk = logical ^ ((row>>1)&3)  (round-3
// pattern, measured 0 bank conflicts).
#define LDSA(par) ((par) * 24576)
#define LDSB(par) ((par) * 24576 + 16384)

#define STAGE3(par, t) do { \
  const u16* ga_ = Ab + (size_t)grow * K_ + (t) * 32 + gch8; \
  char* la_ = ldsc + LDSA(par) + wid * 1024; \
  gload16(ga_, la_); \
  gload16(ga_ + (size_t)128 * K_, la_ + 8192); \
  gload16(Bb + (size_t)grow * K_ + (t) * 32 + gch8, \
          ldsc + LDSB(par) + wid * 1024); \
} while (0)

#define VMW(n) asm volatile("s_waitcnt vmcnt(" #n ")" ::: "memory")
#define MFMA16 __builtin_amdgcn_mfma_f32_16x16x32_bf16

// One phase: 2 (or 6) ds_read_b128 + optional stage + optional vmcnt +
// barrier + lgkm drain + 8 MFMA. Single barrier per phase; stage targets a
// buffer whose last read was drained before the *previous* barrier (formal).
#define PHASE(par, mh, RB, STAGE_STMT, VMW_STMT) do { \
  const char* pa_ = ldsc + LDSA(par) + aob + (mh) * 2048; \
  av0 = *(const bf16x8*)(pa_); \
  av1 = *(const bf16x8*)(pa_ + 1024); \
  if (RB) { \
    const char* pb_ = ldsc + LDSB(par) + bob; \
    bv0 = *(const bf16x8*)(pb_); \
    bv1 = *(const bf16x8*)(pb_ + 1024); \
    bv2 = *(const bf16x8*)(pb_ + 2048); \
    bv3 = *(const bf16x8*)(pb_ + 3072); \
  } \
  STAGE_STMT; \
  VMW_STMT; \
  __builtin_amdgcn_s_barrier(); \
  asm volatile("s_waitcnt lgkmcnt(0)" ::: "memory"); \
  __builtin_amdgcn_s_setprio(1); \
  acc[(mh) * 2 + 0][0] = MFMA16(av0, bv0, acc[(mh) * 2 + 0][0], 0, 0, 0); \
  acc[(mh) * 2 + 0][1] = MFMA16(av0, bv1, acc[(mh) * 2 + 0][1], 0, 0, 0); \
  acc[(mh) * 2 + 0][2] = MFMA16(av0, bv2, acc[(mh) * 2 + 0][2], 0, 0, 0); \
  acc[(mh) * 2 + 0][3] = MFMA16(av0, bv3, acc[(mh) * 2 + 0][3], 0, 0, 0); \
  acc[(mh) * 2 + 1][0] = MFMA16(av1, bv0, acc[(mh) * 2 + 1][0], 0, 0, 0); \
  acc[(mh) * 2 + 1][1] = MFMA16(av1, bv1, acc[(mh) * 2 + 1][1], 0, 0, 0); \
  acc[(mh) * 2 + 1][2] = MFMA16(av1, bv2, acc[(mh) * 2 + 1][2], 0, 0, 0); \
  acc[(mh) * 2 + 1][3] = MFMA16(av1, bv3, acc[(mh) * 2 + 1][3], 0, 0, 0); \
  __builtin_amdgcn_s_setprio(0); \
} while (0)

__global__ __launch_bounds__(512, 4) void lstm_gemm(const u16* __restrict__ A,
                                                    const u16* __restrict__ Wt,
                                                    const float* __restrict__ c_prev,
                                                    float* __restrict__ out) {
  __shared__ __align__(16) u16 lds[36864];   // 72 KiB
  char* ldsc = (char*)lds;
  const int tid  = threadIdx.x;
  const int lane = tid & 63;
  const int wid  = tid >> 6;
  const int wr   = wid >> 1;   // 0..3: 64-row slice
  const int wcn  = wid & 1;    // 0..1: 64-col slice
  const int fr   = lane & 15;
  const int fq   = lane >> 4;

  // XCD-aware swizzle (1024 % 8 == 0 -> bijective); bm fastest so an XCD's
  // blocks share 8 B-panels + all 16 A-panels (40 MB/XCD vs 68 other way).
  const int orig = blockIdx.x;
  const int wg   = ((orig & 7) << 7) | (orig >> 3);
  const int bm   = wg & 15;    // 0..15 (rows of 256)
  const int bn   = wg >> 4;    // 0..63 (cols of 128)

  const u16* Ab = A  + (size_t)bm * 256 * K_;
  const u16* Bb = Wt + (size_t)bn * 128 * K_;

  // staging: thread -> (row, swizzled 16B chunk) of a [.][32] K-slice
  const int grow = tid >> 2;                                 // 0..127
  const int gch8 = (((tid & 3) ^ ((grow >> 1) & 3)) << 3);   // element offset
  // fragment reads: logical chunk fq at row r lives at fq ^ ((r>>1)&3)
  const int csw = (fq ^ ((fr >> 1) & 3)) << 4;
  const int aob = (wr * 64 + fr) * 64 + csw;    // + mh*2048 + m*1024
  const int bob = (wcn * 64 + fr) * 64 + csw;   // + n*1024

  f32x4 acc[4][4] = {};   // [mi = mh*2+m][gate]
  bf16x8 av0, av1, bv0, bv1, bv2, bv3;

  // ---- prologue: tiles 0,1 staged; t0 drained ----
  STAGE3(0, 0);
  STAGE3(1, 1);
  VMW(3);
  __builtin_amdgcn_s_barrier();

  for (int tb = 0; tb < NT; tb += 3) {
    PHASE(0, 0, 1, {}, {});
    PHASE(0, 1, 0, { if (tb + 2 < NT) STAGE3(2, tb + 2); },
          { if (tb + 2 < NT) { VMW(3); } else { VMW(0); } });
    if (tb + 1 >= NT) break;
    PHASE(1, 0, 1, {}, {});
    PHASE(1, 1, 0, { if (tb + 3 < NT) STAGE3(0, tb + 3); },
          { if (tb + 3 < NT) { VMW(3); } else { VMW(0); } });
    if (tb + 2 >= NT) break;
    PHASE(2, 0, 1, {}, {});
    PHASE(2, 1, 0, { if (tb + 4 < NT) STAGE3(1, tb + 4); },
          { if (tb + 4 < NT) { VMW(3); } else { VMW(0); } });
  }

  // ---- fused LSTM epilogue (C/D 16x16: col=fr, row=fq*4+r) ----
  const int u  = (bn * 2 + wcn) * 16 + fr;
  const size_t BU = (size_t)B_ * U_;
#pragma unroll
  for (int mi = 0; mi < 4; ++mi) {
#pragma unroll
    for (int r = 0; r < 4; ++r) {
      int row = bm * 256 + wr * 64 + mi * 16 + fq * 4 + r;
      float zi = acc[mi][0][r], zf = acc[mi][1][r];
      float zc = acc[mi][2][r], zo = acc[mi][3][r];
      float iv = hsig(zi), fv = hsig(zf), ov = hsig(zo);
      size_t off = (size_t)row * U_ + u;
      float cp = c_prev[off];
      float cv = fv * cp + iv * ftanh(zc);
      float hv = ov * ftanh(cv);
      out[off]          = hv;
      out[BU + off]     = hv;
      out[2 * BU + off] = cv;
    }
  }
}

extern "C" void kernel_launch(void* const* d_in, const int* in_sizes, int n_in,
                              void* d_out, int out_size, void* d_ws, size_t ws_size,
                              hipStream_t stream) {
  const float* x  = (const float*)d_in[0];
  const float* h  = (const float*)d_in[1];
  const float* cp = (const float*)d_in[2];
  const float* kk = (const float*)d_in[3];
  const float* rk = (const float*)d_in[4];
  float* out = (float*)d_out;

  const size_t bytesA  = (size_t)B_ * K_ * 2;   // 32 MiB
  const size_t bytesWt = (size_t)N_ * K_ * 2;   // 64 MiB
  if (ws_size < bytesA + bytesWt) return;

  u16* Aws = (u16*)d_ws;
  u16* Wt  = (u16*)((char*)d_ws + bytesA);

  cast_a<<<(B_ * K_ / 8) / 256, 256, 0, stream>>>(x, h, Aws);
  cast_wt<<<dim3(N_ / 64, K_ / 64), 256, 0, stream>>>(kk, rk, Wt);
  lstm_gemm<<<dim3(1024), dim3(512), 0, stream>>>(Aws, Wt, cp, out);
}

// Round 6
// 305.749 us; speedup vs baseline: 3.4641x; 3.4641x over previous
//
#include <hip/hip_runtime.h>
#include <stdint.h>

typedef unsigned short u16;
typedef float f32x4 __attribute__((ext_vector_type(4)));
typedef __bf16 bf16x8 __attribute__((ext_vector_type(8)));

#define B_ 4096
#define D_ 2048
#define U_ 2048
#define K_ 4096   // D + U
#define N_ 8192   // 4*U
#define NT_ 128   // K/32 K-tiles

__device__ __forceinline__ u16 f32_bf16(float f) {
  uint32_t u = __float_as_uint(f);
  u += 0x7FFFu + ((u >> 16) & 1u);
  return (u16)(u >> 16);
}
__device__ __forceinline__ float hsig(float x) {
  return fminf(fmaxf(0.2f * x + 0.5f, 0.0f), 1.0f);
}
__device__ __forceinline__ float ftanh(float x) {
  x = fminf(fmaxf(x, -15.0f), 15.0f);
  float e = __expf(2.0f * x);
  return (e - 1.0f) / (e + 1.0f);
}
__device__ __forceinline__ void gload16(const void* g, void* l) {
  __builtin_amdgcn_global_load_lds(
      (const __attribute__((address_space(1))) void*)g,
      (__attribute__((address_space(3))) void*)l,
      16, 0, 0);
}

// ---- cast A = [inputs | h_tm1] -> bf16 [4096][4096] ----
__global__ __launch_bounds__(256) void cast_a(const float* __restrict__ x,
                                              const float* __restrict__ h,
                                              u16* __restrict__ A) {
  int c = blockIdx.x * 256 + threadIdx.x;
  int m = c >> 9;
  int kc = (c & 511) << 3;
  const float* src = (kc < D_) ? (x + (size_t)m * D_ + kc)
                               : (h + (size_t)m * U_ + (kc - D_));
  float4 v0 = ((const float4*)src)[0];
  float4 v1 = ((const float4*)src)[1];
  u16 o[8] = { f32_bf16(v0.x), f32_bf16(v0.y), f32_bf16(v0.z), f32_bf16(v0.w),
               f32_bf16(v1.x), f32_bf16(v1.y), f32_bf16(v1.z), f32_bf16(v1.w) };
  *(uint4*)(A + (size_t)c * 8) = *(const uint4*)o;
}

// ---- cast + transpose + gate-interleave W -> Wt[n'][k] bf16 [8192][4096] ----
// n' = ublk*64 + g*16 + ul  where u = ublk*16 + ul, original col n = g*2048 + u
__global__ __launch_bounds__(256) void cast_wt(const float* __restrict__ kern,
                                               const float* __restrict__ rker,
                                               u16* __restrict__ Wt) {
  __shared__ u16 sW[64][68];
  const int t = threadIdx.x;
  const int bx = blockIdx.x;   // ublk 0..127
  const int by = blockIdx.y;   // k block 0..63
  const int k0 = by * 64;
  const float* src = (k0 < D_) ? kern : rker;
  const int krow0 = (k0 < D_) ? k0 : (k0 - D_);
#pragma unroll
  for (int i = 0; i < 4; ++i) {
    int c = i * 256 + t;
    int kl = c >> 4;
    int nq = c & 15;
    int g  = nq >> 2;
    int ul = (nq & 3) << 2;
    int n  = g * U_ + bx * 16 + ul;
    float4 v = *(const float4*)(src + (size_t)(krow0 + kl) * N_ + n);
    u16 p[4] = { f32_bf16(v.x), f32_bf16(v.y), f32_bf16(v.z), f32_bf16(v.w) };
    *(ushort4*)&sW[kl][g * 16 + ul] = *(const ushort4*)p;
  }
  __syncthreads();
#pragma unroll
  for (int j = 0; j < 2; ++j) {
    int c2 = j * 256 + t;
    int nl = c2 >> 3;
    int kc = c2 & 7;
    u16 p[8];
#pragma unroll
    for (int jj = 0; jj < 8; ++jj) p[jj] = sW[kc * 8 + jj][nl];
    *(uint4*)(Wt + ((size_t)bx * 64 + nl) * K_ + k0 + kc * 8) = *(const uint4*)p;
  }
}

// ======= 256x256 GEMM: 4-parity BK=32, 32 MFMA + 1 barrier per phase =======
// LDS: 4 parities x (A[256][32] 16K + B[256][32] 16K) = 128 KiB.
// Row = 64B = 4 chunks; phys_chunk = logical ^ ((row>>1)&3)  (0-conflict,
// measured round 3). Stage at phase p targets parity (p+2)%4: distance >=2
// from any parity read at p or p-1 (the max barrier skew window). VMW(4)
// per phase drains stage(p-1) exactly one phase before its read.
#define LDSA(par) ((par) * 32768)
#define LDSB(par) ((par) * 32768 + 16384)

#define STAGE4(par, t) do { \
  const u16* ga_ = Ab + (size_t)grow * K_ + (t) * 32 + gch8; \
  const u16* gb_ = Bb + (size_t)grow * K_ + (t) * 32 + gch8; \
  char* la_ = ldsc + LDSA(par) + wid * 1024; \
  char* lb_ = ldsc + LDSB(par) + wid * 1024; \
  gload16(ga_, la_); \
  gload16(ga_ + (size_t)128 * K_, la_ + 8192); \
  gload16(gb_, lb_); \
  gload16(gb_ + (size_t)128 * K_, lb_ + 8192); \
} while (0)

#define VMW(n) asm volatile("s_waitcnt vmcnt(" #n ")" ::: "memory")
#define MFMA16 __builtin_amdgcn_mfma_f32_16x16x32_bf16

// Phase: 12 ds_read_b128 + 4 gloads + counted vmcnt + barrier + lgkm + 32 MFMA.
#define PHASE(par, STAGE_STMT, VMW_STMT) do { \
  const char* pa_ = ldsc + LDSA(par) + aob; \
  const char* pb_ = ldsc + LDSB(par) + bob; \
  _Pragma("unroll") \
  for (int m_ = 0; m_ < 8; ++m_) av[m_] = *(const bf16x8*)(pa_ + m_ * 1024); \
  _Pragma("unroll") \
  for (int n_ = 0; n_ < 4; ++n_) bv[n_] = *(const bf16x8*)(pb_ + n_ * 1024); \
  STAGE_STMT; \
  VMW_STMT; \
  __builtin_amdgcn_s_barrier(); \
  asm volatile("s_waitcnt lgkmcnt(0)" ::: "memory"); \
  __builtin_amdgcn_sched_barrier(0); \
  __builtin_amdgcn_s_setprio(1); \
  _Pragma("unroll") \
  for (int m_ = 0; m_ < 8; ++m_) { \
    _Pragma("unroll") \
    for (int n_ = 0; n_ < 4; ++n_) \
      acc[m_][n_] = MFMA16(av[m_], bv[n_], acc[m_][n_], 0, 0, 0); \
  } \
  __builtin_amdgcn_s_setprio(0); \
} while (0)

__global__ __launch_bounds__(512, 2) void lstm_gemm(const u16* __restrict__ A,
                                                    const u16* __restrict__ Wt,
                                                    const float* __restrict__ c_prev,
                                                    float* __restrict__ out) {
  __shared__ __align__(16) u16 lds[65536];   // 128 KiB
  char* ldsc = (char*)lds;
  const int tid  = threadIdx.x;
  const int lane = tid & 63;
  const int wid  = tid >> 6;
  const int wr   = wid >> 2;   // 0..1: 128-row slice
  const int wcn  = wid & 3;    // 0..3: 64-col slice (4 gates x 16 u)
  const int fr   = lane & 15;
  const int fq   = lane >> 4;

  // XCD-aware swizzle (512 % 8 == 0 -> bijective)
  const int orig = blockIdx.x;
  const int wg   = ((orig & 7) << 6) | (orig >> 3);
  const int bm   = wg & 15;
  const int bn   = wg >> 4;

  const u16* Ab = A  + (size_t)bm * 256 * K_;
  const u16* Bb = Wt + (size_t)bn * 256 * K_;

  // staging: thread -> (row, swizzled 16B chunk) of a [256][32] tile slice
  const int grow = tid >> 2;                                 // 0..127
  const int gch8 = (((tid & 3) ^ ((grow >> 1) & 3)) << 3);   // element offset
  // fragment reads: logical chunk fq at row r lives at fq ^ ((r>>1)&3)
  const int csw = (fq ^ ((fr >> 1) & 3)) << 4;
  const int aob = (wr * 128 + fr) * 64 + csw;   // + m*1024
  const int bob = (wcn * 64 + fr) * 64 + csw;   // + n*1024

  f32x4 acc[8][4] = {};   // [m-frag][gate]
  bf16x8 av[8], bv[4];

  // ---- prologue: tiles 0,1 staged; tile0 drained ----
  STAGE4(0, 0);
  STAGE4(1, 1);
  VMW(4);
  __builtin_amdgcn_s_barrier();

  for (int tb = 0; tb < NT_; tb += 4) {
    PHASE(0, { STAGE4(2, tb + 2); }, { VMW(4); });   // tb+2 <= 126 always
    PHASE(1, { STAGE4(3, tb + 3); }, { VMW(4); });   // tb+3 <= 127 always
    PHASE(2, { if (tb + 4 < NT_) STAGE4(0, tb + 4); },
          { if (tb + 4 < NT_) { VMW(4); } else { VMW(0); } });
    PHASE(3, { if (tb + 5 < NT_) STAGE4(1, tb + 5); },
          { if (tb + 5 < NT_) { VMW(4); } });
  }

  // ---- fused LSTM epilogue (C/D 16x16: col=fr, row=fq*4+r) ----
  const int u  = (bn * 4 + wcn) * 16 + fr;
  const size_t BU = (size_t)B_ * U_;
#pragma unroll
  for (int mi = 0; mi < 8; ++mi) {
#pragma unroll
    for (int r = 0; r < 4; ++r) {
      int row = bm * 256 + wr * 128 + mi * 16 + fq * 4 + r;
      float zi = acc[mi][0][r], zf = acc[mi][1][r];
      float zc = acc[mi][2][r], zo = acc[mi][3][r];
      float iv = hsig(zi), fv = hsig(zf), ov = hsig(zo);
      size_t off = (size_t)row * U_ + u;
      float cp = c_prev[off];
      float cv = fv * cp + iv * ftanh(zc);
      float hv = ov * ftanh(cv);
      out[off]          = hv;
      out[BU + off]     = hv;
      out[2 * BU + off] = cv;
    }
  }
}

extern "C" void kernel_launch(void* const* d_in, const int* in_sizes, int n_in,
                              void* d_out, int out_size, void* d_ws, size_t ws_size,
                              hipStream_t stream) {
  const float* x  = (const float*)d_in[0];
  const float* h  = (const float*)d_in[1];
  const float* cp = (const float*)d_in[2];
  const float* kk = (const float*)d_in[3];
  const float* rk = (const float*)d_in[4];
  float* out = (float*)d_out;

  const size_t bytesA  = (size_t)B_ * K_ * 2;   // 32 MiB
  const size_t bytesWt = (size_t)N_ * K_ * 2;   // 64 MiB
  if (ws_size < bytesA + bytesWt) return;

  u16* Aws = (u16*)d_ws;
  u16* Wt  = (u16*)((char*)d_ws + bytesA);

  cast_a<<<(B_ * K_ / 8) / 256, 256, 0, stream>>>(x, h, Aws);
  cast_wt<<<dim3(N_ / 64, K_ / 64), 256, 0, stream>>>(kk, rk, Wt);
  lstm_gemm<<<dim3(512), dim3(512), 0, stream>>>(Aws, Wt, cp, out);
}